// Round 6
// baseline (29.157 us; speedup 1.0000x reference)
//
#include <hip/hip_runtime.h>

// buckets = gray( packbits( mat[row,:] @ proj[:,r] > 0 ) ),  gray(b) = b ^ (b>>1)
// mat: [2,32,8192,64] f32   proj: [64,8] f32   out: [524288] i32
//
// LDS-free: 16 lanes per row (lane = row g=lane>>4 x chunk h=lane&15); each
// global_load_dwordx4 covers one 4-row group = 1 KiB fully coalesced.
// R5: select-free butterfly. pf columns are XOR-permuted per lane
// (pf[j][p] = proj[.. + (p ^ m)], m = 4h2+2h1+h3), so every DPP exchange has
// static keep/send register positions -- zero v_cndmask. Lane h ends holding
// the full dot for r = m; one __ballot yields 4 bins.
// Schedule: 1024 blocks (exactly 4/CU, single resident cohort), 32 groups per
// wave, depth-3 register ring (12 KiB in flight), fully straight-line.

constexpr int NBLK = 1024;
constexpr int GPW  = 32;                   // 1024 blk x 4 waves x 32 = 131072 groups

#define DPP_XOR1 0xB1    // quad_perm [1,0,3,2]
#define DPP_XOR2 0x4E    // quad_perm [2,3,0,1]
#define DPP_XOR7 0x141   // row_half_mirror
#define DPP_XOR8 0x128   // row_ror:8  (rotate by 8 within 16 == xor 8)

template <int CTRL>
__device__ __forceinline__ float dppf(float x) {
    const int xi = __float_as_int(x);
    const int r = __builtin_amdgcn_update_dpp(xi, xi, CTRL, 0xF, 0xF, false);
    return __int_as_float(r);
}

__global__ __launch_bounds__(256, 4) void lsh_kernel(
    const float* __restrict__ mat,
    const float* __restrict__ proj,
    int*         __restrict__ out)
{
    const int lane = threadIdx.x & 63;
    const int wid  = threadIdx.x >> 6;
    const int h    = lane & 15;            // chunk within row
    const int g    = lane >> 4;            // row within group
    const int m    = ((h >> 2) & 1) * 4 + ((h >> 1) & 1) * 2 + ((h >> 3) & 1);

    // XOR-permuted proj fragment: pf[j][p] = proj[(h*4+j)*8 + (p ^ m)]
    float pf[4][8];
    #pragma unroll
    for (int j = 0; j < 4; ++j)
        #pragma unroll
        for (int p = 0; p < 8; ++p)
            pf[j][p] = proj[(h * 4 + j) * 8 + (p ^ m)];

    const int shift = lane & 48;           // g*16: ballot slice
    const int gbase = (blockIdx.x * 4 + wid) * GPW;
    const float4* src = reinterpret_cast<const float4*>(mat) + (size_t)gbase * 64 + lane;

    float4 A[4], B[4], C[4];

    auto load4 = [&](float4 (&buf)[4]) {
        #pragma unroll
        for (int u = 0; u < 4; ++u)
            buf[u] = src[u * 64];          // 1 KiB apart
        src += 4 * 64;                     // advance 4 KiB
    };

    auto compute4 = [&](const float4 (&buf)[4], int base) {
        #pragma unroll
        for (int u = 0; u < 4; ++u) {
            const float vv[4] = {buf[u].x, buf[u].y, buf[u].z, buf[u].w};
            float s[8];
            #pragma unroll
            for (int p = 0; p < 8; ++p) {
                s[p] = vv[0] * pf[0][p];
                #pragma unroll
                for (int j = 1; j < 4; ++j)
                    s[p] = fmaf(vv[j], pf[j][p], s[p]);
            }
            // select-free butterfly (partner under xor7 has m' = m^6)
            const float t0 = s[0] + dppf<DPP_XOR7>(s[6]);
            const float t1 = s[1] + dppf<DPP_XOR7>(s[7]);
            const float t2 = s[2] + dppf<DPP_XOR7>(s[4]);
            const float t3 = s[3] + dppf<DPP_XOR7>(s[5]);
            const float q0 = t0 + dppf<DPP_XOR2>(t2);
            const float q1 = t1 + dppf<DPP_XOR2>(t3);
            const float d  = q0 + dppf<DPP_XOR8>(q1);
            const float f  = d  + dppf<DPP_XOR1>(d);

            const unsigned long long bal = __ballot(f > 0.0f);
            const unsigned int w = (unsigned int)(bal >> shift);
            const unsigned int bin = (w & 0x55u) | ((w >> 7) & 0xAAu);
            const int bucket = (int)(bin ^ (bin >> 1));   // Gray-code table
            if (h == 0)
                out[(gbase + base + u) * 4 + g] = bucket;
        }
    };

    // depth-3 ring, straight line: 12 KiB in flight before every compute
    load4(A); load4(B); load4(C);
    compute4(A, 0);   load4(A);
    compute4(B, 4);   load4(B);
    compute4(C, 8);   load4(C);
    compute4(A, 12);  load4(A);
    compute4(B, 16);  load4(B);
    compute4(C, 20);
    compute4(A, 24);
    compute4(B, 28);
}

extern "C" void kernel_launch(void* const* d_in, const int* in_sizes, int n_in,
                              void* d_out, int out_size, void* d_ws, size_t ws_size,
                              hipStream_t stream) {
    const float* mat  = (const float*)d_in[0];   // [2,32,8192,64] f32
    const float* proj = (const float*)d_in[1];   // [1,1,64,8] f32
    // d_in[2] = perm (Gray code, computed analytically), d_in[3] = enc_vec
    int* out = (int*)d_out;                      // [524288] i32

    lsh_kernel<<<NBLK, 256, 0, stream>>>(mat, proj, out);
}